// Round 11
// baseline (493.607 us; speedup 1.0000x reference)
//
#include <hip/hip_runtime.h>
#include <hip/hip_bf16.h>

#define NN 20000
#define TT 60
#define DD 20
#define HH 128
#define KK 148      // DD + HH
#define EE 320000
#define EA 340000   // EE + NN (self loops)
#define ZSTRIDE 168 // z row stride in u16 (mult of 8 -> b128-aligned rows)
#define MROWS 80    // nodes per LSTM block: 250 blocks = ONE round at 1 block/CU

typedef unsigned short u16;
typedef unsigned int u32;
typedef __attribute__((ext_vector_type(8))) short bf16x8;  // 8 bf16 = 4 VGPRs
typedef __attribute__((ext_vector_type(4))) float f32x4;

#define LOG2E  1.44269504088896340f
#define LOG2E2 2.88539008177792681f

__device__ __forceinline__ float bf2f(u16 u){ return __uint_as_float(((u32)u)<<16); }
__device__ __forceinline__ u16 f2bf(float f){   // RNE, values bounded (no NaN inputs)
  u32 x = __float_as_uint(f);
  return (u16)((x + 0x7FFFu + ((x >> 16) & 1u)) >> 16);
}
// single-instruction RNE f32->bf16 (low half of v_cvt_pk result)
__device__ __forceinline__ u16 f2bf_cvt(float f){
  float r;
  asm("v_cvt_pk_bf16_f32 %0, %1, %2" : "=v"(r) : "v"(f), "v"(f));
  return (u16)__float_as_uint(r);
}

// ---------------- fused prep: LSTM Wfrag + GAT W-frags + deg zeroing --------------------
// blocks [0,320): LSTM Wfrag (81920 elems). blocks [320,448): W1f/W2f (32768 elems).
// blocks [448,527): deg[i]=0 (replaces hipMemsetAsync dispatch).
// LSTM layout: Wfrag[((wc*20+q*5+kt)*64+lane)*8+j]; col=q*128+wc*16+(lane&15);
// k=kt*32+(lane>>4)*8+j; k==148 row carries prescaled bias (z col 148 held at 1.0);
// gates i,f,o prescaled by log2e, gate g by 2*log2e (activations use raw v_exp_f32).
__global__ void prep_kernel(const float* __restrict__ Wih, const float* __restrict__ Whh,
                            const float* __restrict__ bih, const float* __restrict__ bhh,
                            u16* __restrict__ Wfrag,
                            const float* __restrict__ W1, const float* __restrict__ W2,
                            u16* __restrict__ W1f, u16* __restrict__ W2f,
                            int* __restrict__ deg){
  const int b = blockIdx.x;
  if (b < 320){
    int idx = b*256 + threadIdx.x;     // < 81920 always
    int j    = idx & 7;
    int lane = (idx >> 3) & 63;
    int rest = idx >> 9;               // wc*20 + q*5 + kt
    int kt = rest % 5, q = (rest/5) & 3, wc = rest/20;
    int col = q*128 + wc*16 + (lane & 15);
    int k   = kt*32 + ((lane >> 4) & 3)*8 + j;
    float v = 0.f;
    if (k < DD)       v = Wih[(size_t)col*DD + k];
    else if (k < KK)  v = Whh[(size_t)col*HH + (k - DD)];
    else if (k == KK) v = bih[col] + bhh[col];
    v *= (q == 2) ? LOG2E2 : LOG2E;
    Wfrag[idx] = f2bf(v);
  } else if (b < 448){
    int idx = (b-320)*256 + threadIdx.x;  // < 32768
    const float* W = W1; u16* Wf = W1f;
    if (idx >= 8*4*64*8){ idx -= 8*4*64*8; W = W2; Wf = W2f; }
    int j = idx & 7, lane = (idx>>3) & 63, kt = (idx>>9) & 3, ct = idx>>11;
    int col = ct*16 + (lane & 15);
    int k   = kt*32 + ((lane>>4) & 3)*8 + j;
    Wf[idx] = f2bf(W[(size_t)k*128 + col]);
  } else {
    int i = (b-448)*256 + threadIdx.x;
    if (i < NN) deg[i] = 0;
  }
}

// ---------------- LSTM: MFMA recurrence, 80 nodes/block, 8 waves, depth-2 pipeline ------
// R9 structure, unchanged (264us best): depth-2 chain pipeline, 7-trans merged act.
__global__ __launch_bounds__(512, 2) void lstm_kernel(const float* __restrict__ xwin,
    const u16* __restrict__ Wfrag, u16* __restrict__ node_h){
  __shared__ u16 z[2][MROWS][ZSTRIDE];   // [buf][node][ x(0..19) | h(20..147) | 1.0 @148 ]
  const int tid  = threadIdx.x;
  const int lane = tid & 63;
  const int wc   = tid >> 6;            // 8 waves: each owns 16 channels x 4 gates
  const int nb   = blockIdx.x * MROWS;
  const int l15  = lane & 15;
  const int quad = lane >> 4;

  // ---- B fragments: 20 x bf16x8 = 80 regs, persistent across 60 steps ----
  bf16x8 B[4][5];
  {
    const bf16x8* bp = (const bf16x8*)Wfrag;
    #pragma unroll
    for (int q = 0; q < 4; q++)
      #pragma unroll
      for (int kt = 0; kt < 5; kt++)
        B[q][kt] = bp[(size_t)((wc*20 + q*5 + kt)*64 + lane)];
  }

  // ---- zero both z buffers ----
  for (int i = tid; i < 2*MROWS*(ZSTRIDE/2); i += 512) ((u32*)(&z[0][0][0]))[i] = 0;

  // x loaders: 1600 elems; thread covers {tid, tid+512, tid+1024, tid+1536}
  const float* xp[4]; int nrow[4], ecol[4], vld[4];
  #pragma unroll
  for (int k2 = 0; k2 < 4; k2++){
    int s = tid + k2*512;
    vld[k2] = (s < MROWS*DD);
    int ss = vld[k2] ? s : 0;
    nrow[k2] = ss/DD; ecol[k2] = ss - nrow[k2]*DD;
    xp[k2] = xwin + (size_t)(nb + nrow[k2])*(TT*DD) + ecol[k2];
  }

  __syncthreads();
  #pragma unroll
  for (int k2 = 0; k2 < 4; k2++)
    if (vld[k2]) z[0][nrow[k2]][ecol[k2]] = f2bf_cvt(xp[k2][0]);
  if (tid < 2*MROWS){                 // constant-1 column feeds the bias row of Wfrag
    int b = tid >= MROWS, r = tid - b*MROWS;
    z[b][r][KK] = 0x3F80;             // 1.0 in bf16
  }

  const f32x4 zf = {0.f, 0.f, 0.f, 0.f};
  f32x4 cst[5];
  #pragma unroll
  for (int mt = 0; mt < 5; mt++) cst[mt] = zf;
  __syncthreads();

  #pragma unroll 1
  for (int t = 0; t < TT; t++){
    const int cur = t & 1, nxt = cur ^ 1;
    const int pre = (t + 1 < TT);

    float xf[4];
    #pragma unroll
    for (int k2 = 0; k2 < 4; k2++)
      xf[k2] = (pre && vld[k2]) ? xp[k2][(t+1)*DD] : 0.f;

    // helpers (all call sites have compile-time mt -> static indexing throughout)
    auto load_A = [&](const int mt, bf16x8 A[5]){
      #pragma unroll
      for (int kt = 0; kt < 5; kt++)
        A[kt] = *(const bf16x8*)&z[cur][mt*16 + l15][kt*32 + quad*8];
    };
    auto chains = [&](const bf16x8 A[5], f32x4 acc[4]){
      #pragma unroll
      for (int q = 0; q < 4; q++){
        f32x4 a = __builtin_amdgcn_mfma_f32_16x16x32_bf16(A[0], B[q][0], zf, 0,0,0);
        a = __builtin_amdgcn_mfma_f32_16x16x32_bf16(A[1], B[q][1], a, 0,0,0);
        a = __builtin_amdgcn_mfma_f32_16x16x32_bf16(A[2], B[q][2], a, 0,0,0);
        a = __builtin_amdgcn_mfma_f32_16x16x32_bf16(A[3], B[q][3], a, 0,0,0);
        a = __builtin_amdgcn_mfma_f32_16x16x32_bf16(A[4], B[q][4], a, 0,0,0);
        acc[q] = a;
      }
    };
    // triple-rcp-merged activation: 5 exp2 + 2 rcp per element.
    auto act = [&](const f32x4 acc[4], const int mt){
      f32x4 cv = cst[mt];
      #pragma unroll
      for (int r = 0; r < 4; r++){
        float pi = __builtin_amdgcn_exp2f(-acc[0][r]);
        float pf = __builtin_amdgcn_exp2f(-acc[1][r]);
        float qg = __builtin_amdgcn_exp2f(-acc[2][r]);
        float po = __builtin_amdgcn_exp2f(-acc[3][r]);
        float X  = (1.f + pi) * (1.f + qg);
        float Y  = 1.f + pf;
        float N  = fmaf(cv[r], X, (1.f - qg) * Y);
        float cc = N * __builtin_amdgcn_rcpf(X * Y);
        cv[r] = cc;
        float qc = __builtin_amdgcn_exp2f(-LOG2E2*cc);
        float h  = (1.f - qc) * __builtin_amdgcn_rcpf((1.f + po)*(1.f + qc));
        const int row = mt*16 + quad*4 + r;
        u16 hb = f2bf_cvt(h);
        z[nxt][row][DD + wc*16 + l15] = hb;
        if (t == TT-1)
          node_h[(size_t)(nb + row)*HH + wc*16 + l15] = hb;
      }
      cst[mt] = cv;
    };

    // depth-2 software pipeline: two chain-blocks in flight ahead of each act
    bf16x8 Aa[5], Ab[5];
    f32x4 acA[4], acB[4], acC[4];
    load_A(0, Aa); chains(Aa, acA);
    load_A(1, Ab); chains(Ab, acB);
    load_A(2, Aa); chains(Aa, acC);  act(acA, 0);
    load_A(3, Ab); chains(Ab, acA);  act(acB, 1);
    load_A(4, Aa); chains(Aa, acB);  act(acC, 2);
    act(acA, 3);
    act(acB, 4);

    if (pre){
      #pragma unroll
      for (int k2 = 0; k2 < 4; k2++)
        if (vld[k2]) z[nxt][nrow[k2]][ecol[k2]] = f2bf_cvt(xf[k2]);
    }
    __syncthreads();
  }
}

// ---------------- MFMA GEMM + fused att logits ------------------------------------------
// Wave w computes cols 32w..32w+31 == head w exactly, so asr[n,w]/adt[n,w] are wave-local
// 16-lane shfl_xor reductions over the in-register f32 accumulators.
__global__ __launch_bounds__(256) void gemm_kernel(const u16* __restrict__ X,
    const u16* __restrict__ Wf, u16* __restrict__ Y,
    const float* __restrict__ att_s, const float* __restrict__ att_d,
    float* __restrict__ asr, float* __restrict__ adt){
  __shared__ u16 xs[32][136];           // +8 pad
  const int tid = threadIdx.x, lane = tid & 63, w = tid >> 6;
  const int l15 = lane & 15, quad = lane >> 4;
  const int rb  = blockIdx.x*32;

  for (int c = tid; c < 512; c += 256){
    int row = c >> 4, cc = c & 15;
    *(bf16x8*)&xs[row][cc*8] = *(const bf16x8*)&X[(size_t)(rb+row)*128 + cc*8];
  }
  bf16x8 Bf[2][4];
  #pragma unroll
  for (int ct = 0; ct < 2; ct++)
    #pragma unroll
    for (int kt = 0; kt < 4; kt++)
      Bf[ct][kt] = *(const bf16x8*)&Wf[(size_t)((((2*w+ct)*4 + kt)*64 + lane))*8];
  // per-lane att weights for this wave's two 16-col groups
  const float as0 = att_s[(2*w+0)*16 + l15], as1 = att_s[(2*w+1)*16 + l15];
  const float ad0 = att_d[(2*w+0)*16 + l15], ad1 = att_d[(2*w+1)*16 + l15];
  __syncthreads();

  bf16x8 A[2][4];
  #pragma unroll
  for (int mt = 0; mt < 2; mt++)
    #pragma unroll
    for (int kt = 0; kt < 4; kt++)
      A[mt][kt] = *(const bf16x8*)&xs[mt*16 + l15][kt*32 + quad*8];

  const f32x4 zf = {0.f,0.f,0.f,0.f};
  #pragma unroll
  for (int mt = 0; mt < 2; mt++){
    f32x4 a[2];
    #pragma unroll
    for (int ct = 0; ct < 2; ct++){
      f32x4 acc = __builtin_amdgcn_mfma_f32_16x16x32_bf16(A[mt][0], Bf[ct][0], zf, 0,0,0);
      acc = __builtin_amdgcn_mfma_f32_16x16x32_bf16(A[mt][1], Bf[ct][1], acc, 0,0,0);
      acc = __builtin_amdgcn_mfma_f32_16x16x32_bf16(A[mt][2], Bf[ct][2], acc, 0,0,0);
      acc = __builtin_amdgcn_mfma_f32_16x16x32_bf16(A[mt][3], Bf[ct][3], acc, 0,0,0);
      a[ct] = acc;
      #pragma unroll
      for (int r = 0; r < 4; r++)
        Y[(size_t)(rb + mt*16 + quad*4 + r)*128 + (2*w+ct)*16 + l15] = f2bf(acc[r]);
    }
    #pragma unroll
    for (int r = 0; r < 4; r++){
      float sv = a[0][r]*as0 + a[1][r]*as1;
      float dv = a[0][r]*ad0 + a[1][r]*ad1;
      #pragma unroll
      for (int off = 1; off < 16; off <<= 1){
        sv += __shfl_xor(sv, off);
        dv += __shfl_xor(dv, off);
      }
      if (l15 == 0){
        const int row = rb + mt*16 + quad*4 + r;
        asr[(size_t)row*4 + w] = sv;
        adt[(size_t)row*4 + w] = dv;
      }
    }
  }
}

// ---------------- CSR build -------------------------------------------------------------
__device__ __forceinline__ void edge_sd(int e, const int* src, const int* dst, int& s, int& d){
  if (e < EE){ s = src[e]; d = dst[e]; } else { s = e - EE; d = s; }
}

__global__ void deg_kernel(const int* __restrict__ src, const int* __restrict__ dst,
                           int* __restrict__ deg){
  int e = blockIdx.x*256 + threadIdx.x;
  if (e >= EA) return;
  int s, d; edge_sd(e, src, dst, s, d);
  atomicAdd(deg + d, 1);
}

// single-block scan over deg[0..NN): replaces psum+pscan+rowptr (3 dispatches -> 1).
// 1024 threads x 20 elems; LDS inclusive scan of 1024 partials; rowptr[NN]=EA (constant).
__global__ __launch_bounds__(1024) void scan_kernel(const int* __restrict__ deg,
    int* __restrict__ rowptr, int* __restrict__ cursor){
  __shared__ int ps[1024];
  const int tid = threadIdx.x;
  const int base = tid*20;
  int v[20]; int s = 0;
  #pragma unroll
  for (int j = 0; j < 20; j++){
    int i = base + j;
    v[j] = (i < NN) ? deg[i] : 0;
    s += v[j];
  }
  ps[tid] = s;
  __syncthreads();
  #pragma unroll
  for (int off = 1; off < 1024; off <<= 1){
    int t = (tid >= off) ? ps[tid-off] : 0;
    __syncthreads();
    ps[tid] += t;
    __syncthreads();
  }
  int excl = ps[tid] - s;   // exclusive prefix of this thread's chunk
  #pragma unroll
  for (int j = 0; j < 20; j++){
    int i = base + j;
    if (i < NN){ rowptr[i] = excl; cursor[i] = excl; excl += v[j]; }
  }
  if (tid == 0) rowptr[NN] = EA;
}

__global__ void fill_kernel(const int* __restrict__ src, const int* __restrict__ dst,
                            int* __restrict__ cursor, int* __restrict__ elist){
  int e = blockIdx.x*256 + threadIdx.x;
  if (e >= EA) return;
  int s, d; edge_sd(e, src, dst, s, d);
  int pos = atomicAdd(cursor + d, 1);
  elist[pos] = s;
}

// ---------------- fused GAT: 1-pass softmax+aggregate+bias+ELU (+optional head) ---------
// Depth-2 software-pipelined edge loop; scalar asr[s*4+h] loads.
__global__ __launch_bounds__(512) void gat_kernel(const int* __restrict__ rowptr,
    const int* __restrict__ elist, const float* __restrict__ asr,
    const float* __restrict__ adt, const u16* __restrict__ XH,
    const float* __restrict__ bias, u16* __restrict__ out,
    const float* __restrict__ Wh, const float* __restrict__ bh,
    float* __restrict__ outf){
  const int tid = threadIdx.x, lane = tid & 63, w = tid >> 6;
  const int d = blockIdx.x*8 + w;            // NN % 8 == 0
  const int r0 = rowptr[d], r1 = rowptr[d+1];
  const int h = lane >> 4;
  const int c = lane*2;
  const float adh = adt[(size_t)d*4 + h];

  float den = 0.f, accx = 0.f, accy = 0.f;
  // depth-2 pipelined edge loop (>=1 edge guaranteed: self loop)
  const u32* X32 = (const u32*)XH;
  int s1 = elist[r0];
  float a0 = asr[(size_t)s1*4 + h];
  u32 p0 = X32[(size_t)s1*64 + lane];
  s1 = (r0+1 < r1) ? elist[r0+1] : s1;
  float a1 = asr[(size_t)s1*4 + h];
  u32 p1 = X32[(size_t)s1*64 + lane];
  for (int idx = r0; idx < r1; idx++){
    int s2 = (idx+2 < r1) ? elist[idx+2] : s1;
    float a2 = asr[(size_t)s2*4 + h];
    u32 p2 = X32[(size_t)s2*64 + lane];
    float l = a0 + adh; l = l > 0.f ? l : 0.2f*l;
    float ex = __expf(l);
    den += ex;
    accx = fmaf(ex, bf2f((u16)p0),       accx);
    accy = fmaf(ex, bf2f((u16)(p0>>16)), accy);
    a0 = a1; p0 = p1;
    a1 = a2; p1 = p2; s1 = s2;
  }
  float rd = __builtin_amdgcn_rcpf(den);
  float vx = accx*rd + bias[c], vy = accy*rd + bias[c+1];
  vx = vx > 0.f ? vx : __expf(vx) - 1.f;
  vy = vy > 0.f ? vy : __expf(vy) - 1.f;

  if (Wh == nullptr){
    u32 pk = (u32)f2bf(vx) | ((u32)f2bf(vy) << 16);
    ((u32*)out)[(size_t)d*64 + lane] = pk;
  } else {
    float p0h = vx*Wh[c*2]   + vy*Wh[c*2+2];
    float p1h = vx*Wh[c*2+1] + vy*Wh[c*2+3];
    #pragma unroll
    for (int off = 32; off > 0; off >>= 1){
      p0h += __shfl_xor(p0h, off);
      p1h += __shfl_xor(p1h, off);
    }
    if (lane == 0){
      float2 o; o.x = p0h + bh[0]; o.y = p1h + bh[1];
      ((float2*)outf)[d] = o;
    }
  }
}

// ---------------- launch ----------------------------------------------------------------
extern "C" void kernel_launch(void* const* d_in, const int* in_sizes, int n_in,
                              void* d_out, int out_size, void* d_ws, size_t ws_size,
                              hipStream_t stream){
  const float* xwin = (const float*)d_in[0];
  const int*   eidx = (const int*)d_in[1];
  const float* Wih  = (const float*)d_in[2];
  const float* Whh  = (const float*)d_in[3];
  const float* bih  = (const float*)d_in[4];
  const float* bhh  = (const float*)d_in[5];
  const float* W1   = (const float*)d_in[6];
  const float* as1  = (const float*)d_in[7];
  const float* ad1  = (const float*)d_in[8];
  const float* b1   = (const float*)d_in[9];
  const float* W2   = (const float*)d_in[10];
  const float* as2  = (const float*)d_in[11];
  const float* ad2  = (const float*)d_in[12];
  const float* b2   = (const float*)d_in[13];
  const float* Wh   = (const float*)d_in[14];
  const float* bh   = (const float*)d_in[15];
  const int* src = eidx;
  const int* dst = eidx + EE;

  char* ws = (char*)d_ws;
  size_t off = 0;
  auto alloc = [&](size_t bytes)->void*{
    void* p = ws + off; off += (bytes + 255) & ~(size_t)255; return p;
  };
  u16*   WfL   = (u16*)  alloc((size_t)8*4*5*64*8*sizeof(u16));
  u16*   W1f   = (u16*)  alloc((size_t)8*4*64*8*sizeof(u16));
  u16*   W2f   = (u16*)  alloc((size_t)8*4*64*8*sizeof(u16));
  u16*   nodeh = (u16*)  alloc((size_t)NN*128*sizeof(u16));
  u16*   xh    = (u16*)  alloc((size_t)NN*128*sizeof(u16));
  u16*   hbuf  = (u16*)  alloc((size_t)NN*128*sizeof(u16));
  float* asr   = (float*)alloc((size_t)NN*4*sizeof(float));
  float* adt   = (float*)alloc((size_t)NN*4*sizeof(float));
  int*   deg   = (int*)  alloc((size_t)NN*sizeof(int));
  int*   rowp  = (int*)  alloc((size_t)(NN+1)*sizeof(int));
  int*   curs  = (int*)  alloc((size_t)NN*sizeof(int));
  int*   elist = (int*)  alloc((size_t)EA*sizeof(int));
  (void)ws_size; (void)in_sizes; (void)n_in; (void)out_size;

  const int EGRID = (EA+255)/256;
  const int PREPB = 320 + 128 + (NN+255)/256;   // lstm-prep | w-prep | deg-zero

  // fused prep (+deg zero), CSR build: 4 dispatches (was 8 incl. memset)
  prep_kernel<<<PREPB, 256, 0, stream>>>(Wih, Whh, bih, bhh, WfL, W1, W2, W1f, W2f, deg);
  deg_kernel<<<EGRID, 256, 0, stream>>>(src, dst, deg);
  scan_kernel<<<1, 1024, 0, stream>>>(deg, rowp, curs);
  fill_kernel<<<EGRID, 256, 0, stream>>>(src, dst, curs, elist);

  // LSTM (250 blocks x 512 threads = one round; depth-2 pipeline + 7-trans act)
  lstm_kernel<<<NN/MROWS, 512, 0, stream>>>(xwin, WfL, nodeh);

  // GAT layer 1 (att logits fused into gemm epilogue)
  gemm_kernel<<<NN/32, 256, 0, stream>>>(nodeh, W1f, xh, as1, ad1, asr, adt);
  gat_kernel<<<NN/8, 512, 0, stream>>>(rowp, elist, asr, adt, xh, b1, hbuf,
                                       nullptr, nullptr, nullptr);
  // GAT layer 2 (+fused head)
  gemm_kernel<<<NN/32, 256, 0, stream>>>(hbuf, W2f, xh, as2, ad2, asr, adt);
  gat_kernel<<<NN/8, 512, 0, stream>>>(rowp, elist, asr, adt, xh, b2, nullptr,
                                       Wh, bh, (float*)d_out);
}

// Round 12
// 476.712 us; speedup vs baseline: 1.0354x; 1.0354x over previous
//
#include <hip/hip_runtime.h>
#include <hip/hip_bf16.h>

#define NN 20000
#define TT 60
#define DD 20
#define HH 128
#define KK 148      // DD + HH
#define EE 320000
#define EA 340000   // EE + NN (self loops)
#define ZSTRIDE 168 // z row stride in u16 (mult of 8 -> b128-aligned rows)
#define MROWS 80    // nodes per LSTM block: 250 blocks = ONE round at 1 block/CU

typedef unsigned short u16;
typedef unsigned int u32;
typedef __attribute__((ext_vector_type(8))) short bf16x8;  // 8 bf16 = 4 VGPRs
typedef __attribute__((ext_vector_type(4))) float f32x4;

#define LOG2E  1.44269504088896340f
#define LOG2E2 2.88539008177792681f

__device__ __forceinline__ float bf2f(u16 u){ return __uint_as_float(((u32)u)<<16); }
__device__ __forceinline__ u16 f2bf(float f){   // RNE, values bounded (no NaN inputs)
  u32 x = __float_as_uint(f);
  return (u16)((x + 0x7FFFu + ((x >> 16) & 1u)) >> 16);
}
// single-instruction RNE f32->bf16 (low half of v_cvt_pk result)
__device__ __forceinline__ u16 f2bf_cvt(float f){
  float r;
  asm("v_cvt_pk_bf16_f32 %0, %1, %2" : "=v"(r) : "v"(f), "v"(f));
  return (u16)__float_as_uint(r);
}

// ---------------- fused prep: LSTM Wfrag + GAT W-frags + deg zeroing --------------------
// blocks [0,320): LSTM Wfrag. blocks [320,448): W1f/W2f. blocks [448,...): deg=0.
// LSTM layout: Wfrag[((wc*20+q*5+kt)*64+lane)*8+j]; col=q*128+wc*16+(lane&15);
// k=kt*32+(lane>>4)*8+j; k==148 row carries prescaled bias (z col 148 held at 1.0);
// gates i,f,o prescaled by log2e, gate g by 2*log2e (activations use raw v_exp_f32).
__global__ void prep_kernel(const float* __restrict__ Wih, const float* __restrict__ Whh,
                            const float* __restrict__ bih, const float* __restrict__ bhh,
                            u16* __restrict__ Wfrag,
                            const float* __restrict__ W1, const float* __restrict__ W2,
                            u16* __restrict__ W1f, u16* __restrict__ W2f,
                            int* __restrict__ deg){
  const int b = blockIdx.x;
  if (b < 320){
    int idx = b*256 + threadIdx.x;     // < 81920 always
    int j    = idx & 7;
    int lane = (idx >> 3) & 63;
    int rest = idx >> 9;               // wc*20 + q*5 + kt
    int kt = rest % 5, q = (rest/5) & 3, wc = rest/20;
    int col = q*128 + wc*16 + (lane & 15);
    int k   = kt*32 + ((lane >> 4) & 3)*8 + j;
    float v = 0.f;
    if (k < DD)       v = Wih[(size_t)col*DD + k];
    else if (k < KK)  v = Whh[(size_t)col*HH + (k - DD)];
    else if (k == KK) v = bih[col] + bhh[col];
    v *= (q == 2) ? LOG2E2 : LOG2E;
    Wfrag[idx] = f2bf(v);
  } else if (b < 448){
    int idx = (b-320)*256 + threadIdx.x;  // < 32768
    const float* W = W1; u16* Wf = W1f;
    if (idx >= 8*4*64*8){ idx -= 8*4*64*8; W = W2; Wf = W2f; }
    int j = idx & 7, lane = (idx>>3) & 63, kt = (idx>>9) & 3, ct = idx>>11;
    int col = ct*16 + (lane & 15);
    int k   = kt*32 + ((lane>>4) & 3)*8 + j;
    Wf[idx] = f2bf(W[(size_t)k*128 + col]);
  } else {
    int i = (b-448)*256 + threadIdx.x;
    if (i < NN) deg[i] = 0;
  }
}

// ---------------- LSTM: MFMA recurrence, 80 nodes/block, 8 waves, depth-2 pipeline ------
// R9 structure, unchanged (264us best): depth-2 chain pipeline, 7-trans merged act.
__global__ __launch_bounds__(512, 2) void lstm_kernel(const float* __restrict__ xwin,
    const u16* __restrict__ Wfrag, u16* __restrict__ node_h){
  __shared__ u16 z[2][MROWS][ZSTRIDE];   // [buf][node][ x(0..19) | h(20..147) | 1.0 @148 ]
  const int tid  = threadIdx.x;
  const int lane = tid & 63;
  const int wc   = tid >> 6;            // 8 waves: each owns 16 channels x 4 gates
  const int nb   = blockIdx.x * MROWS;
  const int l15  = lane & 15;
  const int quad = lane >> 4;

  // ---- B fragments: 20 x bf16x8 = 80 regs, persistent across 60 steps ----
  bf16x8 B[4][5];
  {
    const bf16x8* bp = (const bf16x8*)Wfrag;
    #pragma unroll
    for (int q = 0; q < 4; q++)
      #pragma unroll
      for (int kt = 0; kt < 5; kt++)
        B[q][kt] = bp[(size_t)((wc*20 + q*5 + kt)*64 + lane)];
  }

  // ---- zero both z buffers ----
  for (int i = tid; i < 2*MROWS*(ZSTRIDE/2); i += 512) ((u32*)(&z[0][0][0]))[i] = 0;

  // x loaders: 1600 elems; thread covers {tid, tid+512, tid+1024, tid+1536}
  const float* xp[4]; int nrow[4], ecol[4], vld[4];
  #pragma unroll
  for (int k2 = 0; k2 < 4; k2++){
    int s = tid + k2*512;
    vld[k2] = (s < MROWS*DD);
    int ss = vld[k2] ? s : 0;
    nrow[k2] = ss/DD; ecol[k2] = ss - nrow[k2]*DD;
    xp[k2] = xwin + (size_t)(nb + nrow[k2])*(TT*DD) + ecol[k2];
  }

  __syncthreads();
  #pragma unroll
  for (int k2 = 0; k2 < 4; k2++)
    if (vld[k2]) z[0][nrow[k2]][ecol[k2]] = f2bf_cvt(xp[k2][0]);
  if (tid < 2*MROWS){                 // constant-1 column feeds the bias row of Wfrag
    int b = tid >= MROWS, r = tid - b*MROWS;
    z[b][r][KK] = 0x3F80;             // 1.0 in bf16
  }

  const f32x4 zf = {0.f, 0.f, 0.f, 0.f};
  f32x4 cst[5];
  #pragma unroll
  for (int mt = 0; mt < 5; mt++) cst[mt] = zf;
  __syncthreads();

  #pragma unroll 1
  for (int t = 0; t < TT; t++){
    const int cur = t & 1, nxt = cur ^ 1;
    const int pre = (t + 1 < TT);

    float xf[4];
    #pragma unroll
    for (int k2 = 0; k2 < 4; k2++)
      xf[k2] = (pre && vld[k2]) ? xp[k2][(t+1)*DD] : 0.f;

    // helpers (all call sites have compile-time mt -> static indexing throughout)
    auto load_A = [&](const int mt, bf16x8 A[5]){
      #pragma unroll
      for (int kt = 0; kt < 5; kt++)
        A[kt] = *(const bf16x8*)&z[cur][mt*16 + l15][kt*32 + quad*8];
    };
    auto chains = [&](const bf16x8 A[5], f32x4 acc[4]){
      #pragma unroll
      for (int q = 0; q < 4; q++){
        f32x4 a = __builtin_amdgcn_mfma_f32_16x16x32_bf16(A[0], B[q][0], zf, 0,0,0);
        a = __builtin_amdgcn_mfma_f32_16x16x32_bf16(A[1], B[q][1], a, 0,0,0);
        a = __builtin_amdgcn_mfma_f32_16x16x32_bf16(A[2], B[q][2], a, 0,0,0);
        a = __builtin_amdgcn_mfma_f32_16x16x32_bf16(A[3], B[q][3], a, 0,0,0);
        a = __builtin_amdgcn_mfma_f32_16x16x32_bf16(A[4], B[q][4], a, 0,0,0);
        acc[q] = a;
      }
    };
    // triple-rcp-merged activation: 5 exp2 + 2 rcp per element.
    auto act = [&](const f32x4 acc[4], const int mt){
      f32x4 cv = cst[mt];
      #pragma unroll
      for (int r = 0; r < 4; r++){
        float pi = __builtin_amdgcn_exp2f(-acc[0][r]);
        float pf = __builtin_amdgcn_exp2f(-acc[1][r]);
        float qg = __builtin_amdgcn_exp2f(-acc[2][r]);
        float po = __builtin_amdgcn_exp2f(-acc[3][r]);
        float X  = (1.f + pi) * (1.f + qg);
        float Y  = 1.f + pf;
        float N  = fmaf(cv[r], X, (1.f - qg) * Y);
        float cc = N * __builtin_amdgcn_rcpf(X * Y);
        cv[r] = cc;
        float qc = __builtin_amdgcn_exp2f(-LOG2E2*cc);
        float h  = (1.f - qc) * __builtin_amdgcn_rcpf((1.f + po)*(1.f + qc));
        const int row = mt*16 + quad*4 + r;
        u16 hb = f2bf_cvt(h);
        z[nxt][row][DD + wc*16 + l15] = hb;
        if (t == TT-1)
          node_h[(size_t)(nb + row)*HH + wc*16 + l15] = hb;
      }
      cst[mt] = cv;
    };

    // depth-2 software pipeline: two chain-blocks in flight ahead of each act
    bf16x8 Aa[5], Ab[5];
    f32x4 acA[4], acB[4], acC[4];
    load_A(0, Aa); chains(Aa, acA);
    load_A(1, Ab); chains(Ab, acB);
    load_A(2, Aa); chains(Aa, acC);  act(acA, 0);
    load_A(3, Ab); chains(Ab, acA);  act(acB, 1);
    load_A(4, Aa); chains(Aa, acB);  act(acC, 2);
    act(acA, 3);
    act(acB, 4);

    if (pre){
      #pragma unroll
      for (int k2 = 0; k2 < 4; k2++)
        if (vld[k2]) z[nxt][nrow[k2]][ecol[k2]] = f2bf_cvt(xf[k2]);
    }
    __syncthreads();
  }
}

// ---------------- MFMA GEMM + fused att logits ------------------------------------------
// Wave w computes cols 32w..32w+31 == head w exactly, so asr[n,w]/adt[n,w] are wave-local
// 16-lane shfl_xor reductions over the in-register f32 accumulators.
__global__ __launch_bounds__(256) void gemm_kernel(const u16* __restrict__ X,
    const u16* __restrict__ Wf, u16* __restrict__ Y,
    const float* __restrict__ att_s, const float* __restrict__ att_d,
    float* __restrict__ asr, float* __restrict__ adt){
  __shared__ u16 xs[32][136];           // +8 pad
  const int tid = threadIdx.x, lane = tid & 63, w = tid >> 6;
  const int l15 = lane & 15, quad = lane >> 4;
  const int rb  = blockIdx.x*32;

  for (int c = tid; c < 512; c += 256){
    int row = c >> 4, cc = c & 15;
    *(bf16x8*)&xs[row][cc*8] = *(const bf16x8*)&X[(size_t)(rb+row)*128 + cc*8];
  }
  bf16x8 Bf[2][4];
  #pragma unroll
  for (int ct = 0; ct < 2; ct++)
    #pragma unroll
    for (int kt = 0; kt < 4; kt++)
      Bf[ct][kt] = *(const bf16x8*)&Wf[(size_t)((((2*w+ct)*4 + kt)*64 + lane))*8];
  // per-lane att weights for this wave's two 16-col groups
  const float as0 = att_s[(2*w+0)*16 + l15], as1 = att_s[(2*w+1)*16 + l15];
  const float ad0 = att_d[(2*w+0)*16 + l15], ad1 = att_d[(2*w+1)*16 + l15];
  __syncthreads();

  bf16x8 A[2][4];
  #pragma unroll
  for (int mt = 0; mt < 2; mt++)
    #pragma unroll
    for (int kt = 0; kt < 4; kt++)
      A[mt][kt] = *(const bf16x8*)&xs[mt*16 + l15][kt*32 + quad*8];

  const f32x4 zf = {0.f,0.f,0.f,0.f};
  #pragma unroll
  for (int mt = 0; mt < 2; mt++){
    f32x4 a[2];
    #pragma unroll
    for (int ct = 0; ct < 2; ct++){
      f32x4 acc = __builtin_amdgcn_mfma_f32_16x16x32_bf16(A[mt][0], Bf[ct][0], zf, 0,0,0);
      acc = __builtin_amdgcn_mfma_f32_16x16x32_bf16(A[mt][1], Bf[ct][1], acc, 0,0,0);
      acc = __builtin_amdgcn_mfma_f32_16x16x32_bf16(A[mt][2], Bf[ct][2], acc, 0,0,0);
      acc = __builtin_amdgcn_mfma_f32_16x16x32_bf16(A[mt][3], Bf[ct][3], acc, 0,0,0);
      a[ct] = acc;
      #pragma unroll
      for (int r = 0; r < 4; r++)
        Y[(size_t)(rb + mt*16 + quad*4 + r)*128 + (2*w+ct)*16 + l15] = f2bf(acc[r]);
    }
    #pragma unroll
    for (int r = 0; r < 4; r++){
      float sv = a[0][r]*as0 + a[1][r]*as1;
      float dv = a[0][r]*ad0 + a[1][r]*ad1;
      #pragma unroll
      for (int off = 1; off < 16; off <<= 1){
        sv += __shfl_xor(sv, off);
        dv += __shfl_xor(dv, off);
      }
      if (l15 == 0){
        const int row = rb + mt*16 + quad*4 + r;
        asr[(size_t)row*4 + w] = sv;
        adt[(size_t)row*4 + w] = dv;
      }
    }
  }
}

// ---------------- CSR build (parallel scan, R10-proven) ---------------------------------
__device__ __forceinline__ void edge_sd(int e, const int* src, const int* dst, int& s, int& d){
  if (e < EE){ s = src[e]; d = dst[e]; } else { s = e - EE; d = s; }
}

__global__ void deg_kernel(const int* __restrict__ src, const int* __restrict__ dst,
                           int* __restrict__ deg){
  int e = blockIdx.x*256 + threadIdx.x;
  if (e >= EA) return;
  int s, d; edge_sd(e, src, dst, s, d);
  atomicAdd(deg + d, 1);
}

#define SCB 80   // ceil(NN/256)
__global__ __launch_bounds__(256) void psum_kernel(const int* __restrict__ deg,
                                                   int* __restrict__ psum){
  __shared__ int ws[4];
  int i = blockIdx.x*256 + threadIdx.x;
  int v = (i < NN) ? deg[i] : 0;
  #pragma unroll
  for (int off = 32; off > 0; off >>= 1) v += __shfl_down(v, off);
  if ((threadIdx.x & 63) == 0) ws[threadIdx.x >> 6] = v;
  __syncthreads();
  if (threadIdx.x == 0) psum[blockIdx.x] = ws[0]+ws[1]+ws[2]+ws[3];
}

__global__ void pscan_kernel(const int* __restrict__ psum, int* __restrict__ boff,
                             int* __restrict__ rowptr){
  if (threadIdx.x == 0){
    int acc = 0;
    for (int b = 0; b < SCB; b++){ boff[b] = acc; acc += psum[b]; }
    boff[SCB] = acc;
    rowptr[NN] = acc;   // == EA
  }
}

__global__ __launch_bounds__(256) void rowptr_kernel(const int* __restrict__ deg,
    const int* __restrict__ boff, int* __restrict__ rowptr, int* __restrict__ cursor){
  __shared__ int buf[256];
  const int tid = threadIdx.x;
  int i = blockIdx.x*256 + tid;
  int v = (i < NN) ? deg[i] : 0;
  buf[tid] = v;
  __syncthreads();
  #pragma unroll
  for (int off = 1; off < 256; off <<= 1){
    int t = (tid >= off) ? buf[tid - off] : 0;
    __syncthreads();
    buf[tid] += t;
    __syncthreads();
  }
  if (i < NN){
    int excl = buf[tid] - v + boff[blockIdx.x];
    rowptr[i] = excl; cursor[i] = excl;
  }
}

__global__ void fill_kernel(const int* __restrict__ src, const int* __restrict__ dst,
                            int* __restrict__ cursor, int* __restrict__ elist){
  int e = blockIdx.x*256 + threadIdx.x;
  if (e >= EA) return;
  int s, d; edge_sd(e, src, dst, s, d);
  int pos = atomicAdd(cursor + d, 1);
  elist[pos] = s;
}

// ---------------- fused GAT: 1-pass softmax+aggregate+bias+ELU (+optional head) ---------
// Depth-2 software-pipelined edge loop; scalar asr[s*4+h] loads.
__global__ __launch_bounds__(512) void gat_kernel(const int* __restrict__ rowptr,
    const int* __restrict__ elist, const float* __restrict__ asr,
    const float* __restrict__ adt, const u16* __restrict__ XH,
    const float* __restrict__ bias, u16* __restrict__ out,
    const float* __restrict__ Wh, const float* __restrict__ bh,
    float* __restrict__ outf){
  const int tid = threadIdx.x, lane = tid & 63, w = tid >> 6;
  const int d = blockIdx.x*8 + w;            // NN % 8 == 0
  const int r0 = rowptr[d], r1 = rowptr[d+1];
  const int h = lane >> 4;
  const int c = lane*2;
  const float adh = adt[(size_t)d*4 + h];

  float den = 0.f, accx = 0.f, accy = 0.f;
  // depth-2 pipelined edge loop (>=1 edge guaranteed: self loop)
  const u32* X32 = (const u32*)XH;
  int s1 = elist[r0];
  float a0 = asr[(size_t)s1*4 + h];
  u32 p0 = X32[(size_t)s1*64 + lane];
  s1 = (r0+1 < r1) ? elist[r0+1] : s1;
  float a1 = asr[(size_t)s1*4 + h];
  u32 p1 = X32[(size_t)s1*64 + lane];
  for (int idx = r0; idx < r1; idx++){
    int s2 = (idx+2 < r1) ? elist[idx+2] : s1;
    float a2 = asr[(size_t)s2*4 + h];
    u32 p2 = X32[(size_t)s2*64 + lane];
    float l = a0 + adh; l = l > 0.f ? l : 0.2f*l;
    float ex = __expf(l);
    den += ex;
    accx = fmaf(ex, bf2f((u16)p0),       accx);
    accy = fmaf(ex, bf2f((u16)(p0>>16)), accy);
    a0 = a1; p0 = p1;
    a1 = a2; p1 = p2; s1 = s2;
  }
  float rd = __builtin_amdgcn_rcpf(den);
  float vx = accx*rd + bias[c], vy = accy*rd + bias[c+1];
  vx = vx > 0.f ? vx : __expf(vx) - 1.f;
  vy = vy > 0.f ? vy : __expf(vy) - 1.f;

  if (Wh == nullptr){
    u32 pk = (u32)f2bf(vx) | ((u32)f2bf(vy) << 16);
    ((u32*)out)[(size_t)d*64 + lane] = pk;
  } else {
    float p0h = vx*Wh[c*2]   + vy*Wh[c*2+2];
    float p1h = vx*Wh[c*2+1] + vy*Wh[c*2+3];
    #pragma unroll
    for (int off = 32; off > 0; off >>= 1){
      p0h += __shfl_xor(p0h, off);
      p1h += __shfl_xor(p1h, off);
    }
    if (lane == 0){
      float2 o; o.x = p0h + bh[0]; o.y = p1h + bh[1];
      ((float2*)outf)[d] = o;
    }
  }
}

// ---------------- launch ----------------------------------------------------------------
extern "C" void kernel_launch(void* const* d_in, const int* in_sizes, int n_in,
                              void* d_out, int out_size, void* d_ws, size_t ws_size,
                              hipStream_t stream){
  const float* xwin = (const float*)d_in[0];
  const int*   eidx = (const int*)d_in[1];
  const float* Wih  = (const float*)d_in[2];
  const float* Whh  = (const float*)d_in[3];
  const float* bih  = (const float*)d_in[4];
  const float* bhh  = (const float*)d_in[5];
  const float* W1   = (const float*)d_in[6];
  const float* as1  = (const float*)d_in[7];
  const float* ad1  = (const float*)d_in[8];
  const float* b1   = (const float*)d_in[9];
  const float* W2   = (const float*)d_in[10];
  const float* as2  = (const float*)d_in[11];
  const float* ad2  = (const float*)d_in[12];
  const float* b2   = (const float*)d_in[13];
  const float* Wh   = (const float*)d_in[14];
  const float* bh   = (const float*)d_in[15];
  const int* src = eidx;
  const int* dst = eidx + EE;

  char* ws = (char*)d_ws;
  size_t off = 0;
  auto alloc = [&](size_t bytes)->void*{
    void* p = ws + off; off += (bytes + 255) & ~(size_t)255; return p;
  };
  u16*   WfL   = (u16*)  alloc((size_t)8*4*5*64*8*sizeof(u16));
  u16*   W1f   = (u16*)  alloc((size_t)8*4*64*8*sizeof(u16));
  u16*   W2f   = (u16*)  alloc((size_t)8*4*64*8*sizeof(u16));
  u16*   nodeh = (u16*)  alloc((size_t)NN*128*sizeof(u16));
  u16*   xh    = (u16*)  alloc((size_t)NN*128*sizeof(u16));
  u16*   hbuf  = (u16*)  alloc((size_t)NN*128*sizeof(u16));
  float* asr   = (float*)alloc((size_t)NN*4*sizeof(float));
  float* adt   = (float*)alloc((size_t)NN*4*sizeof(float));
  int*   deg   = (int*)  alloc((size_t)NN*sizeof(int));
  int*   rowp  = (int*)  alloc((size_t)(NN+1)*sizeof(int));
  int*   curs  = (int*)  alloc((size_t)NN*sizeof(int));
  int*   psum  = (int*)  alloc((size_t)SCB*sizeof(int));
  int*   boff  = (int*)  alloc((size_t)(SCB+1)*sizeof(int));
  int*   elist = (int*)  alloc((size_t)EA*sizeof(int));
  (void)ws_size; (void)in_sizes; (void)n_in; (void)out_size;

  const int EGRID = (EA+255)/256;
  const int PREPB = 320 + 128 + (NN+255)/256;   // lstm-prep | w-prep | deg-zero

  // fused prep (+deg zero) + parallel CSR build (R10-proven scan path)
  prep_kernel<<<PREPB, 256, 0, stream>>>(Wih, Whh, bih, bhh, WfL, W1, W2, W1f, W2f, deg);
  deg_kernel<<<EGRID, 256, 0, stream>>>(src, dst, deg);
  psum_kernel<<<SCB, 256, 0, stream>>>(deg, psum);
  pscan_kernel<<<1, 64, 0, stream>>>(psum, boff, rowp);
  rowptr_kernel<<<SCB, 256, 0, stream>>>(deg, boff, rowp, curs);
  fill_kernel<<<EGRID, 256, 0, stream>>>(src, dst, curs, elist);

  // LSTM (250 blocks x 512 threads = one round; depth-2 pipeline + 7-trans act)
  lstm_kernel<<<NN/MROWS, 512, 0, stream>>>(xwin, WfL, nodeh);

  // GAT layer 1 (att logits fused into gemm epilogue)
  gemm_kernel<<<NN/32, 256, 0, stream>>>(nodeh, W1f, xh, as1, ad1, asr, adt);
  gat_kernel<<<NN/8, 512, 0, stream>>>(rowp, elist, asr, adt, xh, b1, hbuf,
                                       nullptr, nullptr, nullptr);
  // GAT layer 2 (+fused head)
  gemm_kernel<<<NN/32, 256, 0, stream>>>(hbuf, W2f, xh, as2, ad2, asr, adt);
  gat_kernel<<<NN/8, 512, 0, stream>>>(rowp, elist, asr, adt, xh, b2, nullptr,
                                       Wh, bh, (float*)d_out);
}